// Round 1
// baseline (1137.688 us; speedup 1.0000x reference)
//
#include <hip/hip_runtime.h>
#include <math.h>

#define NB 100   // Q == G == C == 100

// Elementwise box terms, exact replication of reference fp32 math.
__device__ __forceinline__ void box_terms(const float bp[4], const float bg[4],
                                          float &iou, float &bgr) {
    float p_ul0 = bp[0] - 0.5f * bp[2], p_ul1 = bp[1] - 0.5f * bp[3];
    float p_dr0 = bp[0] + 0.5f * bp[2], p_dr1 = bp[1] + 0.5f * bp[3];
    float g_ul0 = bg[0] - 0.5f * bg[2], g_ul1 = bg[1] - 0.5f * bg[3];
    float g_dr0 = bg[0] + 0.5f * bg[2], g_dr1 = bg[1] + 0.5f * bg[3];
    float iw0 = fmaxf(fminf(p_dr0, g_dr0) - fmaxf(p_ul0, g_ul0) + 1.0f, 0.0f);
    float iw1 = fmaxf(fminf(p_dr1, g_dr1) - fmaxf(p_ul1, g_ul1) + 1.0f, 0.0f);
    float inter = iw0 * iw1;
    float pw0 = fmaxf(p_dr0 - p_ul0 + 1.0f, 0.0f);
    float pw1 = fmaxf(p_dr1 - p_ul1 + 1.0f, 0.0f);
    float gw0 = fmaxf(g_dr0 - g_ul0 + 1.0f, 0.0f);
    float gw1 = fmaxf(g_dr1 - g_ul1 + 1.0f, 0.0f);
    float pa = pw0 * pw1, ga = gw0 * gw1;
    float uni = pa + ga - inter;
    iou = inter / fmaxf(uni, 1e-9f);
    float bw0 = fmaxf(fmaxf(p_dr0, g_dr0) - fminf(p_ul0, g_ul0) + 1.0f, 0.0f);
    float bw1 = fmaxf(fmaxf(p_dr1, g_dr1) - fminf(p_ul1, g_ul1) + 1.0f, 0.0f);
    float bound = bw0 * bw1;
    bgr = (bound - uni) / fmaxf(bound, 1e-9f);
}

// One block per batch: cost matrix -> Hungarian (wave 0) -> losses -> ws[b].
__global__ __launch_bounds__(256) void fused_match_loss(
    const float* __restrict__ bbox_pred,    // B,100,4
    const float* __restrict__ labels_pred,  // B,100,100
    const float* __restrict__ bbox_gt,      // B,100,4
    const int*   __restrict__ labels_gt,    // B,100
    float* __restrict__ per_sample)         // B
{
    __shared__ float  cost_sh[NB * NB];   // 40 KB, fp32 (f64 cast on read is exact)
    __shared__ double u_sh[NB + 1];
    __shared__ int    p_sh[NB];           // column -> assigned row (1-based), 0 = free
    __shared__ int    way_sh[NB];
    __shared__ int    col_sh[NB];         // query -> matched gt
    __shared__ float  bp_sh[NB * 4];
    __shared__ float  bg_sh[NB * 4];
    __shared__ int    lg_sh[NB];
    __shared__ float  red_sh[3 * 128];

    const int b = blockIdx.x;
    const int t = threadIdx.x;
    const float* lp = labels_pred + (size_t)b * NB * NB;

    // ---- stage boxes / gt labels ----
    for (int i = t; i < NB * 4; i += 256) {
        bp_sh[i] = bbox_pred[(size_t)b * NB * 4 + i];
        bg_sh[i] = bbox_gt[(size_t)b * NB * 4 + i];
    }
    for (int i = t; i < NB; i += 256) lg_sh[i] = labels_gt[b * NB + i];
    for (int i = t; i <= NB; i += 256) u_sh[i] = 0.0;
    for (int i = t; i < NB; i += 256) p_sh[i] = 0;
    __syncthreads();

    // ---- cost matrix (fp32, same op order as reference) ----
    for (int idx = t; idx < NB * NB; idx += 256) {
        int q = idx / NB, g = idx - q * NB;
        float bp[4] = {bp_sh[q*4+0], bp_sh[q*4+1], bp_sh[q*4+2], bp_sh[q*4+3]};
        float bg[4] = {bg_sh[g*4+0], bg_sh[g*4+1], bg_sh[g*4+2], bg_sh[g*4+3]};
        float l1 = fabsf(bp[0]-bg[0]) + fabsf(bp[1]-bg[1])
                 + fabsf(bp[2]-bg[2]) + fabsf(bp[3]-bg[3]);
        float iou, bgr;
        box_terms(bp, bg, iou, bgr);
        float prob = lp[q * NB + lg_sh[g]];
        cost_sh[idx] = l1 - (iou - bgr) - prob;
    }
    __syncthreads();

    // ---- Hungarian (JV shortest augmenting path), wave 0 only, f64 ----
    if (t < 64) {
        const int lane = t;
        const int jjA = lane;          // column index 0..99 (alg j = jj+1)
        const int jjB = lane + 64;
        const bool validB = (jjB < NB);
        double vA = 0.0, vB = 0.0;

        for (int i = 1; i <= NB; ++i) {
            const int p0 = i;                     // p[0]
            double mA = (double)INFINITY, mB = (double)INFINITY;
            bool usedA = false, usedB = false;
            int j0 = 0;
            for (;;) {
                // used[j0] = True
                if (j0 > 0) {
                    int jj = j0 - 1;
                    if (jj == jjA) usedA = true;
                    else if (jj == jjB) usedB = true;
                }
                const int i0 = (j0 == 0) ? p0 : p_sh[j0 - 1];
                const double ui0 = u_sh[i0];
                const float* crow = &cost_sh[(i0 - 1) * NB];

                // scan free columns; lane-local best (first-index tie-break)
                double best = (double)INFINITY;
                int bestj = 0x7FFFFFFF;
                if (!usedA) {
                    double cur = (double)crow[jjA] - ui0 - vA;
                    if (cur < mA) { mA = cur; way_sh[jjA] = j0; }
                    best = mA; bestj = jjA + 1;
                }
                if (validB && !usedB) {
                    double cur = (double)crow[jjB] - ui0 - vB;
                    if (cur < mB) { mB = cur; way_sh[jjB] = j0; }
                    if (mB < best) { best = mB; bestj = jjB + 1; }
                }
                // 64-lane butterfly argmin, ties -> smaller column index
                #pragma unroll
                for (int off = 32; off > 0; off >>= 1) {
                    double ov = __shfl_xor(best, off, 64);
                    int    oj = __shfl_xor(bestj, off, 64);
                    if (ov < best || (ov == best && oj < bestj)) { best = ov; bestj = oj; }
                }
                const double delta = best;
                const int j1 = bestj;

                // dual updates (distinct rows -> conflict-free LDS RMW)
                if (usedA) { vA -= delta; u_sh[p_sh[jjA]] += delta; }
                else       { mA -= delta; }
                if (validB) {
                    if (usedB) { vB -= delta; u_sh[p_sh[jjB]] += delta; }
                    else       { mB -= delta; }
                }
                if (lane == 0) u_sh[p0] += delta;   // virtual column 0

                j0 = j1;
                if (p_sh[j0 - 1] == 0) break;
            }
            // augment along way[] (uniform walk, all lanes write same values)
            int jj = j0;
            while (jj != 0) {
                int jp = way_sh[jj - 1];
                int row = (jp == 0) ? p0 : p_sh[jp - 1];
                p_sh[jj - 1] = row;
                jj = jp;
            }
        }
        // col[row] = column  (ans[p[1:]-1] = arange(n))
        if (jjA < NB) col_sh[p_sh[jjA] - 1] = jjA;
        if (validB)   col_sh[p_sh[jjB] - 1] = jjB;
    }
    __syncthreads();

    // ---- losses ----
    float nll = 0.0f, regsum = 0.0f, giou = 0.0f;
    if (t < NB) {
        const int q = t;
        const int cg = col_sh[q];
        const int cidx = lg_sh[cg];
        const float* row = lp + q * NB;
        const float hi = 1.0f - 1e-7f;
        float mx = -INFINITY;
        for (int k = 0; k < NB; ++k) {
            float lg = logf(fminf(fmaxf(row[k], 1e-7f), hi));
            mx = fmaxf(mx, lg);
        }
        float se = 0.0f, logit_c = 0.0f;
        for (int k = 0; k < NB; ++k) {
            float lg = logf(fminf(fmaxf(row[k], 1e-7f), hi));
            se += expf(lg - mx);
            if (k == cidx) logit_c = lg;
        }
        nll = (mx + logf(se)) - logit_c;             // -log_softmax at target

        for (int k = 0; k < 4; ++k)
            regsum += fabsf(bp_sh[q*4+k] - bg_sh[cg*4+k]);

        float bp[4] = {bp_sh[q*4+0], bp_sh[q*4+1], bp_sh[q*4+2], bp_sh[q*4+3]};
        float bq[4] = {bg_sh[q*4+0], bg_sh[q*4+1], bg_sh[q*4+2], bg_sh[q*4+3]};
        float iou, bgr;
        box_terms(bp, bq, iou, bgr);                 // NOTE: elementwise (q,q) per reference
        giou = iou - bgr;
    }
    if (t < 128) {
        red_sh[t]       = nll;
        red_sh[128 + t] = regsum;
        red_sh[256 + t] = giou;
    }
    __syncthreads();
    if (t < 64) {
        float a = red_sh[t]       + red_sh[t + 64];
        float r = red_sh[128 + t] + red_sh[128 + t + 64];
        float g = red_sh[256 + t] + red_sh[256 + t + 64];
        #pragma unroll
        for (int off = 32; off > 0; off >>= 1) {
            a += __shfl_xor(a, off, 64);
            r += __shfl_xor(r, off, 64);
            g += __shfl_xor(g, off, 64);
        }
        if (t == 0)
            per_sample[b] = a * (1.0f / NB) + 5.0f * (r * (1.0f / (NB * 4)))
                          + 2.0f * (g * (1.0f / NB));
    }
}

__global__ void finalize_sum(const float* __restrict__ per_sample, int nb,
                             float* __restrict__ out) {
    if (threadIdx.x == 0 && blockIdx.x == 0) {
        float s = 0.0f;
        for (int i = 0; i < nb; ++i) s += per_sample[i];
        out[0] = s;
    }
}

extern "C" void kernel_launch(void* const* d_in, const int* in_sizes, int n_in,
                              void* d_out, int out_size, void* d_ws, size_t ws_size,
                              hipStream_t stream) {
    const float* bbox_pred   = (const float*)d_in[0];
    const float* labels_pred = (const float*)d_in[1];
    const float* bbox_gt     = (const float*)d_in[2];
    const int*   labels_gt   = (const int*)d_in[3];
    float* ws_f = (float*)d_ws;
    float* out  = (float*)d_out;

    const int B = in_sizes[0] / (NB * 4);   // 16 for the reference shapes

    fused_match_loss<<<B, 256, 0, stream>>>(bbox_pred, labels_pred, bbox_gt,
                                            labels_gt, ws_f);
    finalize_sum<<<1, 64, 0, stream>>>(ws_f, B, out);
}

// Round 2
// 685.056 us; speedup vs baseline: 1.6607x; 1.6607x over previous
//
#include <hip/hip_runtime.h>
#include <math.h>

#define NB 100   // Q == G == C == 100

// Elementwise box terms, exact replication of reference fp32 math.
__device__ __forceinline__ void box_terms(const float bp[4], const float bg[4],
                                          float &iou, float &bgr) {
    float p_ul0 = bp[0] - 0.5f * bp[2], p_ul1 = bp[1] - 0.5f * bp[3];
    float p_dr0 = bp[0] + 0.5f * bp[2], p_dr1 = bp[1] + 0.5f * bp[3];
    float g_ul0 = bg[0] - 0.5f * bg[2], g_ul1 = bg[1] - 0.5f * bg[3];
    float g_dr0 = bg[0] + 0.5f * bg[2], g_dr1 = bg[1] + 0.5f * bg[3];
    float iw0 = fmaxf(fminf(p_dr0, g_dr0) - fmaxf(p_ul0, g_ul0) + 1.0f, 0.0f);
    float iw1 = fmaxf(fminf(p_dr1, g_dr1) - fmaxf(p_ul1, g_ul1) + 1.0f, 0.0f);
    float inter = iw0 * iw1;
    float pw0 = fmaxf(p_dr0 - p_ul0 + 1.0f, 0.0f);
    float pw1 = fmaxf(p_dr1 - p_ul1 + 1.0f, 0.0f);
    float gw0 = fmaxf(g_dr0 - g_ul0 + 1.0f, 0.0f);
    float gw1 = fmaxf(g_dr1 - g_ul1 + 1.0f, 0.0f);
    float pa = pw0 * pw1, ga = gw0 * gw1;
    float uni = pa + ga - inter;
    iou = inter / fmaxf(uni, 1e-9f);
    float bw0 = fmaxf(fmaxf(p_dr0, g_dr0) - fminf(p_ul0, g_ul0) + 1.0f, 0.0f);
    float bw1 = fmaxf(fmaxf(p_dr1, g_dr1) - fminf(p_ul1, g_ul1) + 1.0f, 0.0f);
    float bound = bw0 * bw1;
    bgr = (bound - uni) / fmaxf(bound, 1e-9f);
}

// One block per batch: cost matrix -> Hungarian (wave 0) -> losses -> ws[b].
__global__ __launch_bounds__(256) void fused_match_loss(
    const float* __restrict__ bbox_pred,    // B,100,4
    const float* __restrict__ labels_pred,  // B,100,100
    const float* __restrict__ bbox_gt,      // B,100,4
    const int*   __restrict__ labels_gt,    // B,100
    float* __restrict__ per_sample)         // B
{
    __shared__ float  cost_sh[NB * NB];   // 40 KB fp32 (f64 widen on read is exact)
    __shared__ double u_sh[NB + 1];       // row duals, updated only at phase end
    __shared__ int    col_sh[NB];         // query -> matched gt
    __shared__ float  bp_sh[NB * 4];
    __shared__ float  bg_sh[NB * 4];
    __shared__ int    lg_sh[NB];
    __shared__ float  red_sh[3 * 128];

    const int b = blockIdx.x;
    const int t = threadIdx.x;
    const float* lp = labels_pred + (size_t)b * NB * NB;

    // ---- stage boxes / gt labels ----
    for (int i = t; i < NB * 4; i += 256) {
        bp_sh[i] = bbox_pred[(size_t)b * NB * 4 + i];
        bg_sh[i] = bbox_gt[(size_t)b * NB * 4 + i];
    }
    for (int i = t; i < NB; i += 256) lg_sh[i] = labels_gt[b * NB + i];
    for (int i = t; i <= NB; i += 256) u_sh[i] = 0.0;
    __syncthreads();

    // ---- cost matrix (fp32, same op order as reference) ----
    for (int idx = t; idx < NB * NB; idx += 256) {
        int q = idx / NB, g = idx - q * NB;
        float bp[4] = {bp_sh[q*4+0], bp_sh[q*4+1], bp_sh[q*4+2], bp_sh[q*4+3]};
        float bg[4] = {bg_sh[g*4+0], bg_sh[g*4+1], bg_sh[g*4+2], bg_sh[g*4+3]};
        float l1 = fabsf(bp[0]-bg[0]) + fabsf(bp[1]-bg[1])
                 + fabsf(bp[2]-bg[2]) + fabsf(bp[3]-bg[3]);
        float iou, bgr;
        box_terms(bp, bg, iou, bgr);
        float prob = lp[q * NB + lg_sh[g]];
        cost_sh[idx] = l1 - (iou - bgr) - prob;
    }
    __syncthreads();

    // ---- Hungarian (JV), wave 0, register-resident Dijkstra state ----
    // Per phase: minv[j] (free j) == G(j) - D where
    //   G(j) = min over visited rows of (cost[i0][j] - u0[i0] - v0[j] + D_visit)
    // so no per-step u/v/minv updates are needed; duals settle once per phase.
    if (t < 64) {
        const int lane = t;
        const int colA = lane + 1;            // columns 1..64 (1-based)
        const int colB = lane + 65;           // columns 65..100
        const bool hasB = (colB <= NB);
        const double INF = (double)INFINITY;
        double vA = 0.0, vB = 0.0;
        int pA = 0, pB = 0;                   // column -> matched row (0 = free)

        for (int i = 1; i <= NB; ++i) {
            double GA = INF, GB = INF;
            int wayA = 0, wayB = 0;
            bool usedA = false, usedB = !hasB;
            double DusedA = 0.0, DusedB = 0.0;
            double D = 0.0;
            int i0 = i, j0cur = 0;
            double Df; int jfin;

            for (;;) {
                // row data (two parallel LDS reads on the chain)
                const float* crow = &cost_sh[(i0 - 1) * NB];
                float cA = crow[lane];
                float cB = hasB ? crow[lane + 64] : 0.0f;
                double u0 = u_sh[i0];
                if (!usedA) {
                    double cand = (double)cA - u0 - vA + D;
                    if (cand < GA) { GA = cand; wayA = j0cur; }
                }
                if (!usedB) {
                    double cand = (double)cB - u0 - vB + D;
                    if (cand < GB) { GB = cand; wayB = j0cur; }
                }
                // value-only f64 min butterfly (6 stages)
                double m = fmin(usedA ? INF : GA, usedB ? INF : GB);
                #pragma unroll
                for (int off = 1; off < 64; off <<= 1)
                    m = fmin(m, __shfl_xor(m, off, 64));
                // argmin index: smallest column among exact minima
                unsigned long long ba = __ballot(!usedA && (GA == m));
                int winLane; bool isA;
                if (ba) { winLane = __ffsll((long long)ba) - 1; isA = true; }
                else {
                    unsigned long long bb = __ballot(!usedB && (GB == m));
                    winLane = __ffsll((long long)bb) - 1; isA = false;
                }
                const int j1 = winLane + (isA ? 1 : 65);
                // p[j1] via register shuffle (replaces LDS round-trip)
                int prA = __shfl(pA, winLane, 64);
                int prB = __shfl(pB, winLane, 64);
                int prow = isA ? prA : prB;
                if (prow == 0) { Df = m; jfin = j1; break; }  // j1 stays unmarked
                if (lane == winLane) {
                    if (isA) { usedA = true; DusedA = m; }
                    else     { usedB = true; DusedB = m; }
                }
                i0 = prow; j0cur = j1; D = m;
            }

            // phase-end dual updates (u scatter uses PRE-augment p; rows distinct)
            if (usedA) { u_sh[pA] += Df - DusedA; vA -= Df - DusedA; }
            if (hasB && usedB) { u_sh[pB] += Df - DusedB; vB -= Df - DusedB; }
            if (lane == 0) u_sh[i] += Df;

            // augment along way[] (register shuffles, wave-uniform walk)
            int jcur = jfin;
            while (jcur != 0) {
                int wl = (jcur - 1) & 63;
                int wA = __shfl(wayA, wl, 64);
                int wB = __shfl(wayB, wl, 64);
                int jprev = (jcur <= 64) ? wA : wB;
                int row;
                if (jprev == 0) row = i;
                else {
                    int pl = (jprev - 1) & 63;
                    int rA = __shfl(pA, pl, 64);
                    int rB = __shfl(pB, pl, 64);
                    row = (jprev <= 64) ? rA : rB;
                }
                if (jcur <= 64) { if (lane == jcur - 1)  pA = row; }
                else            { if (lane == jcur - 65) pB = row; }
                jcur = jprev;
            }
        }
        // col[row] = column (0-based gt index)
        if (pA != 0) col_sh[pA - 1] = colA - 1;
        if (hasB && pB != 0) col_sh[pB - 1] = colB - 1;
    }
    __syncthreads();

    // ---- losses ----
    float nll = 0.0f, regsum = 0.0f, giou = 0.0f;
    if (t < NB) {
        const int q = t;
        const int cg = col_sh[q];
        const int cidx = lg_sh[cg];
        const float* row = lp + q * NB;
        const float hi = 1.0f - 1e-7f;
        float mx = -INFINITY;
        for (int k = 0; k < NB; ++k) {
            float lg = logf(fminf(fmaxf(row[k], 1e-7f), hi));
            mx = fmaxf(mx, lg);
        }
        float se = 0.0f, logit_c = 0.0f;
        for (int k = 0; k < NB; ++k) {
            float lg = logf(fminf(fmaxf(row[k], 1e-7f), hi));
            se += expf(lg - mx);
            if (k == cidx) logit_c = lg;
        }
        nll = (mx + logf(se)) - logit_c;             // -log_softmax at target

        for (int k = 0; k < 4; ++k)
            regsum += fabsf(bp_sh[q*4+k] - bg_sh[cg*4+k]);

        float bp[4] = {bp_sh[q*4+0], bp_sh[q*4+1], bp_sh[q*4+2], bp_sh[q*4+3]};
        float bq[4] = {bg_sh[q*4+0], bg_sh[q*4+1], bg_sh[q*4+2], bg_sh[q*4+3]};
        float iou, bgr;
        box_terms(bp, bq, iou, bgr);                 // elementwise (q,q) per reference
        giou = iou - bgr;
    }
    if (t < 128) {
        red_sh[t]       = nll;
        red_sh[128 + t] = regsum;
        red_sh[256 + t] = giou;
    }
    __syncthreads();
    if (t < 64) {
        float a = red_sh[t]       + red_sh[t + 64];
        float r = red_sh[128 + t] + red_sh[128 + t + 64];
        float g = red_sh[256 + t] + red_sh[256 + t + 64];
        #pragma unroll
        for (int off = 32; off > 0; off >>= 1) {
            a += __shfl_xor(a, off, 64);
            r += __shfl_xor(r, off, 64);
            g += __shfl_xor(g, off, 64);
        }
        if (t == 0)
            per_sample[b] = a * (1.0f / NB) + 5.0f * (r * (1.0f / (NB * 4)))
                          + 2.0f * (g * (1.0f / NB));
    }
}

__global__ void finalize_sum(const float* __restrict__ per_sample, int nb,
                             float* __restrict__ out) {
    if (threadIdx.x == 0 && blockIdx.x == 0) {
        float s = 0.0f;
        for (int i = 0; i < nb; ++i) s += per_sample[i];
        out[0] = s;
    }
}

extern "C" void kernel_launch(void* const* d_in, const int* in_sizes, int n_in,
                              void* d_out, int out_size, void* d_ws, size_t ws_size,
                              hipStream_t stream) {
    const float* bbox_pred   = (const float*)d_in[0];
    const float* labels_pred = (const float*)d_in[1];
    const float* bbox_gt     = (const float*)d_in[2];
    const int*   labels_gt   = (const int*)d_in[3];
    float* ws_f = (float*)d_ws;
    float* out  = (float*)d_out;

    const int B = in_sizes[0] / (NB * 4);   // 16 for the reference shapes

    fused_match_loss<<<B, 256, 0, stream>>>(bbox_pred, labels_pred, bbox_gt,
                                            labels_gt, ws_f);
    finalize_sum<<<1, 64, 0, stream>>>(ws_f, B, out);
}

// Round 3
// 528.556 us; speedup vs baseline: 2.1524x; 1.2961x over previous
//
#include <hip/hip_runtime.h>
#include <math.h>

#define NB 100   // Q == G == C == 100

// Elementwise box terms, exact replication of reference fp32 math.
__device__ __forceinline__ void box_terms(const float bp[4], const float bg[4],
                                          float &iou, float &bgr) {
    float p_ul0 = bp[0] - 0.5f * bp[2], p_ul1 = bp[1] - 0.5f * bp[3];
    float p_dr0 = bp[0] + 0.5f * bp[2], p_dr1 = bp[1] + 0.5f * bp[3];
    float g_ul0 = bg[0] - 0.5f * bg[2], g_ul1 = bg[1] - 0.5f * bg[3];
    float g_dr0 = bg[0] + 0.5f * bg[2], g_dr1 = bg[1] + 0.5f * bg[3];
    float iw0 = fmaxf(fminf(p_dr0, g_dr0) - fmaxf(p_ul0, g_ul0) + 1.0f, 0.0f);
    float iw1 = fmaxf(fminf(p_dr1, g_dr1) - fmaxf(p_ul1, g_ul1) + 1.0f, 0.0f);
    float inter = iw0 * iw1;
    float pw0 = fmaxf(p_dr0 - p_ul0 + 1.0f, 0.0f);
    float pw1 = fmaxf(p_dr1 - p_ul1 + 1.0f, 0.0f);
    float gw0 = fmaxf(g_dr0 - g_ul0 + 1.0f, 0.0f);
    float gw1 = fmaxf(g_dr1 - g_ul1 + 1.0f, 0.0f);
    float pa = pw0 * pw1, ga = gw0 * gw1;
    float uni = pa + ga - inter;
    iou = inter / fmaxf(uni, 1e-9f);
    float bw0 = fmaxf(fmaxf(p_dr0, g_dr0) - fminf(p_ul0, g_ul0) + 1.0f, 0.0f);
    float bw1 = fmaxf(fmaxf(p_dr1, g_dr1) - fminf(p_ul1, g_ul1) + 1.0f, 0.0f);
    float bound = bw0 * bw1;
    bgr = (bound - uni) / fmaxf(bound, 1e-9f);
}

// DPP move of a double (both 32-bit halves move identically). VALU latency,
// not DS latency — this is the whole point vs __shfl_xor.
template<int CTRL>
__device__ __forceinline__ double dpp_f64(double x) {
    int lo = __builtin_amdgcn_update_dpp(0, __double2loint(x), CTRL, 0xF, 0xF, true);
    int hi = __builtin_amdgcn_update_dpp(0, __double2hiint(x), CTRL, 0xF, 0xF, true);
    return __hiloint2double(hi, lo);
}

// Full-wave (64-lane) f64 min via DPP tree; returns the min broadcast to all
// lanes (through lane 63 + readlane). Exact: fmin only, order-insensitive.
__device__ __forceinline__ double wave_min_f64(double x) {
    x = fmin(x, dpp_f64<0xB1>(x));    // quad_perm [1,0,3,2]  (xor 1)
    x = fmin(x, dpp_f64<0x4E>(x));    // quad_perm [2,3,0,1]  (xor 2)
    x = fmin(x, dpp_f64<0x141>(x));   // row_half_mirror      (xor 4)
    x = fmin(x, dpp_f64<0x140>(x));   // row_mirror           (xor 8)
    x = fmin(x, dpp_f64<0x142>(x));   // row_bcast15 (row n -> row n+1)
    x = fmin(x, dpp_f64<0x143>(x));   // row_bcast31 (lane31 -> lanes 32..63)
    int lo = __builtin_amdgcn_readlane(__double2loint(x), 63);
    int hi = __builtin_amdgcn_readlane(__double2hiint(x), 63);
    return __hiloint2double(hi, lo);
}

// One block per batch: cost matrix -> Hungarian (wave 0) -> losses -> atomicAdd.
__global__ __launch_bounds__(256) void fused_match_loss(
    const float* __restrict__ bbox_pred,    // B,100,4
    const float* __restrict__ labels_pred,  // B,100,100
    const float* __restrict__ bbox_gt,      // B,100,4
    const int*   __restrict__ labels_gt,    // B,100
    float* __restrict__ out)                // scalar (pre-zeroed)
{
    __shared__ float  cost_sh[NB * NB];   // 40 KB fp32 (f64 widen on read is exact)
    __shared__ double u_sh[NB + 1];       // row duals, updated only at phase end
    __shared__ int    col_sh[NB];         // query -> matched gt
    __shared__ float  bp_sh[NB * 4];
    __shared__ float  bg_sh[NB * 4];
    __shared__ int    lg_sh[NB];
    __shared__ float  red_sh[3 * 128];

    const int b = blockIdx.x;
    const int t = threadIdx.x;
    const float* lp = labels_pred + (size_t)b * NB * NB;

    // ---- stage boxes / gt labels ----
    for (int i = t; i < NB * 4; i += 256) {
        bp_sh[i] = bbox_pred[(size_t)b * NB * 4 + i];
        bg_sh[i] = bbox_gt[(size_t)b * NB * 4 + i];
    }
    for (int i = t; i < NB; i += 256) lg_sh[i] = labels_gt[b * NB + i];
    for (int i = t; i <= NB; i += 256) u_sh[i] = 0.0;
    __syncthreads();

    // ---- cost matrix (fp32, same op order as reference) ----
    for (int idx = t; idx < NB * NB; idx += 256) {
        int q = idx / NB, g = idx - q * NB;
        float bp[4] = {bp_sh[q*4+0], bp_sh[q*4+1], bp_sh[q*4+2], bp_sh[q*4+3]};
        float bg[4] = {bg_sh[g*4+0], bg_sh[g*4+1], bg_sh[g*4+2], bg_sh[g*4+3]};
        float l1 = fabsf(bp[0]-bg[0]) + fabsf(bp[1]-bg[1])
                 + fabsf(bp[2]-bg[2]) + fabsf(bp[3]-bg[3]);
        float iou, bgr;
        box_terms(bp, bg, iou, bgr);
        float prob = lp[q * NB + lg_sh[g]];
        cost_sh[idx] = l1 - (iou - bgr) - prob;
    }
    __syncthreads();

    // ---- Hungarian (JV), wave 0, register-resident Dijkstra state ----
    // minv[j] (free j) == G(j) - D, so duals settle once per phase; the hot
    // loop has NO per-step LDS writes, DPP min-tree, readlane p-lookups.
    if (t < 64) {
        const int lane = t;
        const int colA = lane + 1;            // columns 1..64 (1-based)
        const int colB = lane + 65;           // columns 65..100
        const bool hasB = (colB <= NB);
        const double INF = (double)INFINITY;
        double vA = 0.0, vB = 0.0;
        int pA = 0, pB = 0;                   // column -> matched row (0 = free)

        for (int i = 1; i <= NB; ++i) {
            double GA = INF, GB = INF;
            int wayA = 0, wayB = 0;
            bool usedA = false, usedB = !hasB;
            double DusedA = 0.0, DusedB = 0.0;
            double D = 0.0;
            int i0 = i, j0cur = 0;
            double Df; int jfin;

            for (;;) {
                // row data (independent LDS reads, pipelined)
                const float* crow = &cost_sh[(i0 - 1) * NB];
                float cA = crow[lane];
                float cB = hasB ? crow[lane + 64] : 0.0f;
                double u0 = u_sh[i0];
                if (!usedA) {
                    double cand = (double)cA - u0 - vA + D;
                    if (cand < GA) { GA = cand; wayA = j0cur; }
                }
                if (!usedB) {
                    double cand = (double)cB - u0 - vB + D;
                    if (cand < GB) { GB = cand; wayB = j0cur; }
                }
                // exact f64 min over all free columns, VALU-latency DPP tree
                double mA = usedA ? INF : GA;
                double mB = usedB ? INF : GB;
                const double m = wave_min_f64(fmin(mA, mB));
                // argmin: smallest column among exact minima (numpy first-index)
                unsigned long long ba = __ballot(!usedA && (GA == m));
                int winLane; bool isA;
                if (ba) { winLane = __ffsll((long long)ba) - 1; isA = true; }
                else {
                    unsigned long long bb = __ballot(!usedB && (GB == m));
                    winLane = __ffsll((long long)bb) - 1; isA = false;
                }
                const int j1 = winLane + (isA ? 1 : 65);
                // p[j1] via readlane (VALU, replaces DS shuffle)
                int prow = isA ? __builtin_amdgcn_readlane(pA, winLane)
                               : __builtin_amdgcn_readlane(pB, winLane);
                if (prow == 0) { Df = m; jfin = j1; break; }
                if (lane == winLane) {
                    if (isA) { usedA = true; DusedA = m; }
                    else     { usedB = true; DusedB = m; }
                }
                i0 = prow; j0cur = j1; D = m;
            }

            // phase-end dual updates (u scatter uses PRE-augment p; rows distinct)
            if (usedA) { u_sh[pA] += Df - DusedA; vA -= Df - DusedA; }
            if (hasB && usedB) { u_sh[pB] += Df - DusedB; vB -= Df - DusedB; }
            if (lane == 0) u_sh[i] += Df;

            // augment along way[] (readlane walk, wave-uniform)
            int jcur = jfin;
            while (jcur != 0) {
                int wl = (jcur - 1) & 63;
                int jprev = (jcur <= 64) ? __builtin_amdgcn_readlane(wayA, wl)
                                         : __builtin_amdgcn_readlane(wayB, wl);
                int row;
                if (jprev == 0) row = i;
                else {
                    int pl = (jprev - 1) & 63;
                    row = (jprev <= 64) ? __builtin_amdgcn_readlane(pA, pl)
                                        : __builtin_amdgcn_readlane(pB, pl);
                }
                if (jcur <= 64) { if (lane == jcur - 1)  pA = row; }
                else            { if (lane == jcur - 65) pB = row; }
                jcur = jprev;
            }
        }
        // col[row] = column (0-based gt index)
        if (pA != 0) col_sh[pA - 1] = colA - 1;
        if (hasB && pB != 0) col_sh[pB - 1] = colB - 1;
    }
    __syncthreads();

    // ---- losses ----
    float nll = 0.0f, regsum = 0.0f, giou = 0.0f;
    if (t < NB) {
        const int q = t;
        const int cg = col_sh[q];
        const int cidx = lg_sh[cg];
        const float* row = lp + q * NB;
        const float hi = 1.0f - 1e-7f;
        float mx = -INFINITY;
        for (int k = 0; k < NB; ++k) {
            float lg = logf(fminf(fmaxf(row[k], 1e-7f), hi));
            mx = fmaxf(mx, lg);
        }
        float se = 0.0f, logit_c = 0.0f;
        for (int k = 0; k < NB; ++k) {
            float lg = logf(fminf(fmaxf(row[k], 1e-7f), hi));
            se += expf(lg - mx);
            if (k == cidx) logit_c = lg;
        }
        nll = (mx + logf(se)) - logit_c;             // -log_softmax at target

        for (int k = 0; k < 4; ++k)
            regsum += fabsf(bp_sh[q*4+k] - bg_sh[cg*4+k]);

        float bp[4] = {bp_sh[q*4+0], bp_sh[q*4+1], bp_sh[q*4+2], bp_sh[q*4+3]};
        float bq[4] = {bg_sh[q*4+0], bg_sh[q*4+1], bg_sh[q*4+2], bg_sh[q*4+3]};
        float iou, bgr;
        box_terms(bp, bq, iou, bgr);                 // elementwise (q,q) per reference
        giou = iou - bgr;
    }
    if (t < 128) {
        red_sh[t]       = nll;
        red_sh[128 + t] = regsum;
        red_sh[256 + t] = giou;
    }
    __syncthreads();
    if (t < 64) {
        float a = red_sh[t]       + red_sh[t + 64];
        float r = red_sh[128 + t] + red_sh[128 + t + 64];
        float g = red_sh[256 + t] + red_sh[256 + t + 64];
        #pragma unroll
        for (int off = 32; off > 0; off >>= 1) {
            a += __shfl_xor(a, off, 64);
            r += __shfl_xor(r, off, 64);
            g += __shfl_xor(g, off, 64);
        }
        if (t == 0) {
            float ps = a * (1.0f / NB) + 5.0f * (r * (1.0f / (NB * 4)))
                     + 2.0f * (g * (1.0f / NB));
            atomicAdd(out, ps);   // 16 adds total; fp order jitter ~1e-5 << thr
        }
    }
}

extern "C" void kernel_launch(void* const* d_in, const int* in_sizes, int n_in,
                              void* d_out, int out_size, void* d_ws, size_t ws_size,
                              hipStream_t stream) {
    const float* bbox_pred   = (const float*)d_in[0];
    const float* labels_pred = (const float*)d_in[1];
    const float* bbox_gt     = (const float*)d_in[2];
    const int*   labels_gt   = (const int*)d_in[3];
    float* out = (float*)d_out;

    const int B = in_sizes[0] / (NB * 4);   // 16 for the reference shapes

    hipMemsetAsync(out, 0, sizeof(float), stream);   // d_out is poisoned 0xAA
    fused_match_loss<<<B, 256, 0, stream>>>(bbox_pred, labels_pred, bbox_gt,
                                            labels_gt, out);
}

// Round 4
// 467.750 us; speedup vs baseline: 2.4323x; 1.1300x over previous
//
#include <hip/hip_runtime.h>
#include <math.h>

#define NB 100   // Q == G == C == 100

// Elementwise box terms, exact replication of reference fp32 math.
__device__ __forceinline__ void box_terms(const float bp[4], const float bg[4],
                                          float &iou, float &bgr) {
    float p_ul0 = bp[0] - 0.5f * bp[2], p_ul1 = bp[1] - 0.5f * bp[3];
    float p_dr0 = bp[0] + 0.5f * bp[2], p_dr1 = bp[1] + 0.5f * bp[3];
    float g_ul0 = bg[0] - 0.5f * bg[2], g_ul1 = bg[1] - 0.5f * bg[3];
    float g_dr0 = bg[0] + 0.5f * bg[2], g_dr1 = bg[1] + 0.5f * bg[3];
    float iw0 = fmaxf(fminf(p_dr0, g_dr0) - fmaxf(p_ul0, g_ul0) + 1.0f, 0.0f);
    float iw1 = fmaxf(fminf(p_dr1, g_dr1) - fmaxf(p_ul1, g_ul1) + 1.0f, 0.0f);
    float inter = iw0 * iw1;
    float pw0 = fmaxf(p_dr0 - p_ul0 + 1.0f, 0.0f);
    float pw1 = fmaxf(p_dr1 - p_ul1 + 1.0f, 0.0f);
    float gw0 = fmaxf(g_dr0 - g_ul0 + 1.0f, 0.0f);
    float gw1 = fmaxf(g_dr1 - g_ul1 + 1.0f, 0.0f);
    float pa = pw0 * pw1, ga = gw0 * gw1;
    float uni = pa + ga - inter;
    iou = inter / fmaxf(uni, 1e-9f);
    float bw0 = fmaxf(fmaxf(p_dr0, g_dr0) - fminf(p_ul0, g_ul0) + 1.0f, 0.0f);
    float bw1 = fmaxf(fmaxf(p_dr1, g_dr1) - fminf(p_ul1, g_ul1) + 1.0f, 0.0f);
    float bound = bw0 * bw1;
    bgr = (bound - uni) / fmaxf(bound, 1e-9f);
}

// DPP move of a double (both 32-bit halves move identically). VALU latency.
template<int CTRL>
__device__ __forceinline__ double dpp_f64(double x) {
    int lo = __builtin_amdgcn_update_dpp(0, __double2loint(x), CTRL, 0xF, 0xF, true);
    int hi = __builtin_amdgcn_update_dpp(0, __double2hiint(x), CTRL, 0xF, 0xF, true);
    return __hiloint2double(hi, lo);
}

// Full-wave (64-lane) f64 min via DPP tree; valid result accumulates into
// lane 63 (bound_ctrl zeros only feed lanes we never read); broadcast via
// readlane. Exact fmin — order-insensitive.
__device__ __forceinline__ double wave_min_f64(double x) {
    x = fmin(x, dpp_f64<0xB1>(x));    // quad_perm xor1
    x = fmin(x, dpp_f64<0x4E>(x));    // quad_perm xor2
    x = fmin(x, dpp_f64<0x141>(x));   // row_half_mirror
    x = fmin(x, dpp_f64<0x140>(x));   // row_mirror
    x = fmin(x, dpp_f64<0x142>(x));   // row_bcast15
    x = fmin(x, dpp_f64<0x143>(x));   // row_bcast31
    int lo = __builtin_amdgcn_readlane(__double2loint(x), 63);
    int hi = __builtin_amdgcn_readlane(__double2hiint(x), 63);
    return __hiloint2double(hi, lo);
}

// One block per batch: cost matrix -> LAPJV-init Hungarian (wave 0) ->
// losses -> atomicAdd into out.
__global__ __launch_bounds__(256) void fused_match_loss(
    const float* __restrict__ bbox_pred,    // B,100,4
    const float* __restrict__ labels_pred,  // B,100,100
    const float* __restrict__ bbox_gt,      // B,100,4
    const int*   __restrict__ labels_gt,    // B,100
    float* __restrict__ out)                // scalar (pre-zeroed)
{
    __shared__ float  cost_sh[NB * NB];   // 40 KB fp32 (f64 widen is exact)
    __shared__ double u_sh[NB];           // row duals (0-based)
    __shared__ int    rowclaim_sh[NB];    // column-reduction claims / row-assigned
    __shared__ int    col_sh[NB];         // query -> matched gt
    __shared__ float  bp_sh[NB * 4];
    __shared__ float  bg_sh[NB * 4];
    __shared__ int    lg_sh[NB];
    __shared__ float  red_sh[3 * 128];

    const int b = blockIdx.x;
    const int t = threadIdx.x;
    const float* lp = labels_pred + (size_t)b * NB * NB;

    // ---- stage boxes / gt labels; init duals & claims ----
    for (int i = t; i < NB * 4; i += 256) {
        bp_sh[i] = bbox_pred[(size_t)b * NB * 4 + i];
        bg_sh[i] = bbox_gt[(size_t)b * NB * 4 + i];
    }
    for (int i = t; i < NB; i += 256) {
        lg_sh[i] = labels_gt[b * NB + i];
        u_sh[i] = 0.0;
        rowclaim_sh[i] = 0x7FFFFFFF;
    }
    __syncthreads();

    // ---- cost matrix (fp32, same op order as reference) ----
    for (int idx = t; idx < NB * NB; idx += 256) {
        int q = idx / NB, g = idx - q * NB;
        float bp[4] = {bp_sh[q*4+0], bp_sh[q*4+1], bp_sh[q*4+2], bp_sh[q*4+3]};
        float bg[4] = {bg_sh[g*4+0], bg_sh[g*4+1], bg_sh[g*4+2], bg_sh[g*4+3]};
        float l1 = fabsf(bp[0]-bg[0]) + fabsf(bp[1]-bg[1])
                 + fabsf(bp[2]-bg[2]) + fabsf(bp[3]-bg[3]);
        float iou, bgr;
        box_terms(bp, bg, iou, bgr);
        float prob = lp[q * NB + lg_sh[g]];
        cost_sh[idx] = l1 - (iou - bgr) - prob;
    }
    __syncthreads();

    // ---- Hungarian: LAPJV column-reduction init + JV phases (wave 0) ----
    // Optimum of the f64-cast cost matrix is generically unique, so any exact
    // solver matches the reference's assignment; init duals (u=0, v=colmin)
    // are feasible with tight assigned arcs -> phases stay correct.
    if (t < 64) {
        const int lane = t;
        const bool hasB = (lane + 64 < NB);
        const double INF = (double)INFINITY;

        // column reduction: per-lane column min (first-index on f32 ties)
        float bestA = INFINITY, bestB = INFINITY;
        int iminA = 0, iminB = 0;
        for (int i = 0; i < NB; ++i) {
            float cA = cost_sh[i * NB + lane];
            if (cA < bestA) { bestA = cA; iminA = i; }
            if (hasB) {
                float cB = cost_sh[i * NB + lane + 64];
                if (cB < bestB) { bestB = cB; iminB = i; }
            }
        }
        atomicMin(&rowclaim_sh[iminA], lane);
        if (hasB) atomicMin(&rowclaim_sh[iminB], lane + 64);

        double vA = (double)bestA;
        double vB = hasB ? (double)bestB : 0.0;
        // smallest claiming column wins its row
        int pA = (rowclaim_sh[iminA] == lane) ? iminA : -1;
        int pB = (hasB && rowclaim_sh[iminB] == lane + 64) ? iminB : -1;

        // free-row masks (rows with no claim)
        bool fLo = (rowclaim_sh[lane] == 0x7FFFFFFF);
        bool fHi = hasB && (rowclaim_sh[lane + 64] == 0x7FFFFFFF);
        unsigned long long mLo = __ballot(fLo);
        unsigned long long mHi = __ballot(fHi);

        auto phase = [&](int irow) {
            double GA = INF, GB = INF;
            int wayA = -1, wayB = -1;
            bool usedA = false, usedB = !hasB;
            double DusedA = 0.0, DusedB = 0.0;
            double D = 0.0;
            int i0 = irow, jprevmark = -1;
            double Df; int jfin;

            for (;;) {
                const float* crow = &cost_sh[i0 * NB];
                float cA = crow[lane];
                float cB = hasB ? crow[lane + 64] : 0.0f;
                double u0 = u_sh[i0];
                if (!usedA) {
                    double cand = (double)cA - u0 - vA + D;
                    if (cand < GA) { GA = cand; wayA = jprevmark; }
                }
                if (!usedB) {
                    double cand = (double)cB - u0 - vB + D;
                    if (cand < GB) { GB = cand; wayB = jprevmark; }
                }
                const double m = wave_min_f64(fmin(usedA ? INF : GA,
                                                   usedB ? INF : GB));
                unsigned long long ba = __ballot(!usedA && (GA == m));
                int winLane; bool isA;
                if (ba) { winLane = __ffsll((long long)ba) - 1; isA = true; }
                else {
                    unsigned long long bb = __ballot(!usedB && (GB == m));
                    winLane = __ffsll((long long)bb) - 1; isA = false;
                }
                const int j1 = winLane + (isA ? 0 : 64);
                int prow = isA ? __builtin_amdgcn_readlane(pA, winLane)
                               : __builtin_amdgcn_readlane(pB, winLane);
                if (prow < 0) { Df = m; jfin = j1; break; }
                if (lane == winLane) {
                    if (isA) { usedA = true; DusedA = m; }
                    else     { usedB = true; DusedB = m; }
                }
                i0 = prow; jprevmark = j1; D = m;
            }

            // phase-end dual updates (u scatter uses PRE-augment p)
            if (usedA) { u_sh[pA] += Df - DusedA; vA -= Df - DusedA; }
            if (hasB && usedB) { u_sh[pB] += Df - DusedB; vB -= Df - DusedB; }
            if (lane == 0) u_sh[irow] += Df;

            // augment along way[] (readlane walk, wave-uniform)
            int jcur = jfin;
            while (jcur != -1) {
                int wl = jcur & 63;
                int jprev = (jcur < 64) ? __builtin_amdgcn_readlane(wayA, wl)
                                        : __builtin_amdgcn_readlane(wayB, wl);
                int row;
                if (jprev < 0) row = irow;
                else {
                    int pl = jprev & 63;
                    row = (jprev < 64) ? __builtin_amdgcn_readlane(pA, pl)
                                       : __builtin_amdgcn_readlane(pB, pl);
                }
                if (jcur < 64) { if (lane == jcur)      pA = row; }
                else           { if (lane == jcur - 64) pB = row; }
                jcur = jprev;
            }
        };

        while (mLo) { int i = __ffsll((long long)mLo) - 1; mLo &= mLo - 1; phase(i); }
        while (mHi) { int i = 64 + __ffsll((long long)mHi) - 1; mHi &= mHi - 1; phase(i); }

        // col[row] = column (0-based gt index)
        if (pA >= 0) col_sh[pA] = lane;
        if (hasB && pB >= 0) col_sh[pB] = lane + 64;
    }
    __syncthreads();

    // ---- losses ----
    float nll = 0.0f, regsum = 0.0f, giou = 0.0f;
    if (t < NB) {
        const int q = t;
        const int cg = col_sh[q];
        const int cidx = lg_sh[cg];
        const float* row = lp + q * NB;
        const float hi = 1.0f - 1e-7f;
        float mx = -INFINITY;
        for (int k = 0; k < NB; ++k) {
            float lg = logf(fminf(fmaxf(row[k], 1e-7f), hi));
            mx = fmaxf(mx, lg);
        }
        float se = 0.0f, logit_c = 0.0f;
        for (int k = 0; k < NB; ++k) {
            float lg = logf(fminf(fmaxf(row[k], 1e-7f), hi));
            se += expf(lg - mx);
            if (k == cidx) logit_c = lg;
        }
        nll = (mx + logf(se)) - logit_c;             // -log_softmax at target

        for (int k = 0; k < 4; ++k)
            regsum += fabsf(bp_sh[q*4+k] - bg_sh[cg*4+k]);

        float bp[4] = {bp_sh[q*4+0], bp_sh[q*4+1], bp_sh[q*4+2], bp_sh[q*4+3]};
        float bq[4] = {bg_sh[q*4+0], bg_sh[q*4+1], bg_sh[q*4+2], bg_sh[q*4+3]};
        float iou, bgr;
        box_terms(bp, bq, iou, bgr);                 // elementwise (q,q) per ref
        giou = iou - bgr;
    }
    if (t < 128) {
        red_sh[t]       = nll;
        red_sh[128 + t] = regsum;
        red_sh[256 + t] = giou;
    }
    __syncthreads();
    if (t < 64) {
        float a = red_sh[t]       + red_sh[t + 64];
        float r = red_sh[128 + t] + red_sh[128 + t + 64];
        float g = red_sh[256 + t] + red_sh[256 + t + 64];
        #pragma unroll
        for (int off = 32; off > 0; off >>= 1) {
            a += __shfl_xor(a, off, 64);
            r += __shfl_xor(r, off, 64);
            g += __shfl_xor(g, off, 64);
        }
        if (t == 0) {
            float ps = a * (1.0f / NB) + 5.0f * (r * (1.0f / (NB * 4)))
                     + 2.0f * (g * (1.0f / NB));
            atomicAdd(out, ps);   // 16 adds total; order jitter ~1e-5 << thr
        }
    }
}

extern "C" void kernel_launch(void* const* d_in, const int* in_sizes, int n_in,
                              void* d_out, int out_size, void* d_ws, size_t ws_size,
                              hipStream_t stream) {
    const float* bbox_pred   = (const float*)d_in[0];
    const float* labels_pred = (const float*)d_in[1];
    const float* bbox_gt     = (const float*)d_in[2];
    const int*   labels_gt   = (const int*)d_in[3];
    float* out = (float*)d_out;

    const int B = in_sizes[0] / (NB * 4);   // 16 for the reference shapes

    hipMemsetAsync(out, 0, sizeof(float), stream);   // d_out is poisoned 0xAA
    fused_match_loss<<<B, 256, 0, stream>>>(bbox_pred, labels_pred, bbox_gt,
                                            labels_gt, out);
}